// Round 9
// baseline (127.436 us; speedup 1.0000x reference)
//
#include <hip/hip_runtime.h>
#include <math.h>

// Problem constants: b=4, f=64, h=w=64, HW=4096
// Inputs: fdm [4,1,128,128], x [4,64,64,64], W_fuse [64,128,3,3], b_fuse [64], gamma [64], beta [64]
// Outputs concatenated: x0 [4,64,64,64] (1048576 f32) then sm [4,1,64,64] (16384 f32)

#define HW 4096
#define NCH 64

typedef __attribute__((ext_vector_type(8))) short short8;
typedef __attribute__((ext_vector_type(4))) float f32x4;

static __device__ __forceinline__ ushort f2bf(float f) {
    unsigned u = __float_as_uint(f);
    unsigned r = (u + 0x7fffu + ((u >> 16) & 1u)) >> 16;   // RNE
    return (ushort)r;
}
static __device__ __forceinline__ float bf2f(ushort h) {
    return __uint_as_float(((unsigned)h) << 16);
}
// order-preserving float <-> uint map for atomicMax
static __device__ __forceinline__ unsigned mapf(float f) {
    unsigned u = __float_as_uint(f);
    return u ^ ((unsigned)((int)u >> 31) | 0x80000000u);
}
static __device__ __forceinline__ float unmapf(unsigned u) {
    unsigned b = (u & 0x80000000u) ? (u ^ 0x80000000u) : ~u;
    return __uint_as_float(b);
}

// ---------------- K1: pool (blk 0-3) || norm+bf16-prep (blk 4-259) || weight-prep (blk 260-295) ----------------
// inb layout (TWO copies): [b][8 grp][sp 4096][16 halves]; grp 0-3 = sm*x (fixup rescales ~50 cells),
// grp 4-7 = plain x. Channels grp%4*16..+15.
__global__ __launch_bounds__(256) void k_pnp(
    const float* __restrict__ fdm, const float* __restrict__ x, const float* __restrict__ W,
    float* __restrict__ pooledOut, float* __restrict__ threOut,
    int* __restrict__ unsel, int* __restrict__ unselN, unsigned* __restrict__ scores,
    int* __restrict__ scoreDone, float* __restrict__ gnS1, float* __restrict__ gnS2,
    float* __restrict__ rn, float* __restrict__ smOut, ushort* __restrict__ inb,
    ushort* __restrict__ wbh, ushort* __restrict__ wbl) {
    const int t = threadIdx.x;
    if (blockIdx.x < 4) {
        // ---- pool path ----
        const int b = blockIdx.x;
        __shared__ float pooled[4096];
        __shared__ float red[256];
        __shared__ int cnt;
        const float* fb = fdm + b * 16384;
        float lmax = -1.0f;
#pragma unroll
        for (int it = 0; it < 8; ++it) {
            int id2 = it * 256 + t;
            int i = id2 >> 5;
            int j2 = id2 & 31;
            const float* base = fb + i * 256 + j2 * 4;
            float4 a = *(const float4*)base;
            float4 c = *(const float4*)(base + 128);
            float p0 = fmaxf(fmaxf(a.x, a.y), fmaxf(c.x, c.y));
            float p1 = fmaxf(fmaxf(a.z, a.w), fmaxf(c.z, c.w));
            pooled[i * 64 + j2 * 2]     = p0;
            pooled[i * 64 + j2 * 2 + 1] = p1;
            lmax = fmaxf(lmax, fmaxf(p0, p1));
        }
        red[t] = lmax;
        __syncthreads();
        for (int s = 128; s > 0; s >>= 1) {
            if (t < s) red[t] = fmaxf(red[t], red[t + s]);
            __syncthreads();
        }
        __shared__ float thre_s;
        if (t == 0) {
            thre_s = fminf(0.5f, red[0] / 3.0f);   // exact reference fp32 rounding
            cnt = 0;
            gnS1[b] = 0.0f; gnS2[b] = 0.0f;
            scoreDone[b] = 0;
        }
        __syncthreads();
        const float th = thre_s;
#pragma unroll
        for (int it = 0; it < 4; ++it) {
            int idx = (it * 256 + t) * 4;
            *(float4*)(pooledOut + b * 4096 + idx) = *(const float4*)(pooled + idx);
        }
        for (int idx = t; idx < 4096; idx += 256) {
            scores[b * 4096 + idx] = 0u;           // zero-init scoreboard (ws is poisoned)
            if (!(pooled[idx] >= th)) {
                int pos = atomicAdd(&cnt, 1);
                unsel[b * 4096 + pos] = idx;
            }
        }
        __syncthreads();
        if (t == 0) { unselN[b] = cnt; threOut[b] = th; }
    } else if (blockIdx.x < 260) {
        // ---- norm + prep path ----
        __shared__ float s_part[4][64];
        const int n = blockIdx.x - 4;       // 0..255
        const int b = n >> 6;
        const int pbase = (n & 63) * 64;
        const int wv = t >> 6;              // channel group of 16
        const int l = t & 63;               // position within 64-slice
        const int sp = pbase + l;
        const float* xp = x + b * (NCH * HW) + sp;
        float xv[16];
        float ss = 0.f;
#pragma unroll
        for (int i = 0; i < 16; ++i) {
            float a = xp[(wv * 16 + i) * HW];
            xv[i] = a;
            ss += a * a;
        }
        s_part[wv][l] = ss;
        ushort h[16];
#pragma unroll
        for (int i = 0; i < 16; ++i) h[i] = f2bf(xv[i]);
        size_t dst1 = ((size_t)(b * 8 + wv) * 4096 + sp) * 16;       // scaled copy (scale=1 now)
        size_t dst2 = ((size_t)(b * 8 + 4 + wv) * 4096 + sp) * 16;   // plain copy
        *(uint4*)(inb + dst1)     = *(const uint4*)h;
        *(uint4*)(inb + dst1 + 8) = *(const uint4*)(h + 8);
        *(uint4*)(inb + dst2)     = *(const uint4*)h;
        *(uint4*)(inb + dst2 + 8) = *(const uint4*)(h + 8);
        __syncthreads();
        if (t < 64) {
            float s = s_part[0][l] + s_part[1][l] + s_part[2][l] + s_part[3][l];
            int g = b * HW + pbase + l;
            rn[g] = 1.0f / fmaxf(sqrtf(s), 1e-8f);
            smOut[g] = 1.0f;
        }
    } else {
        // ---- weight prep: bf16 hi/lo, layout [tap][oc][ic128] ----
        const int u = (blockIdx.x - 260) * 256 + t;   // 0..9215 = tap*1024 + oc*16 + g
        const int tap = u >> 10;
        const int rem = u & 1023;
        const int oc = rem >> 4;
        const int g = rem & 15;
        ushort hh[8], ll[8];
#pragma unroll
        for (int j = 0; j < 8; ++j) {
            int ic = g * 8 + j;
            float v = W[(oc * 128 + ic) * 9 + tap];
            ushort hb = f2bf(v);
            hh[j] = hb;
            ll[j] = f2bf(v - bf2f(hb));
        }
        *(uint4*)(wbh + (size_t)u * 8) = *(const uint4*)hh;
        *(uint4*)(wbl + (size_t)u * 8) = *(const uint4*)ll;
    }
}

// ---------------- K2: score via MFMA + last-block sm fixup ----------------
// grid (64 p-strips, 4 b), 256 threads = 4 waves. Strip = 64 p, wave covers 16 p (1 n-tile).
// A = q_hat hi/lo gathered into LDS (rq prefolded); B = plain-x bf16 direct from inb grp 4-7.
// The LAST block per batch (done-counter) finalizes smOut and rescales inb grp 0-3 for unselected q.
__global__ __launch_bounds__(256) void k_score(
    const float* __restrict__ rn, const float* __restrict__ pooledM, const float* __restrict__ threArr,
    const int* __restrict__ unsel, const int* __restrict__ unselN,
    ushort* __restrict__ inb, unsigned* __restrict__ scores, int* __restrict__ scoreDone,
    float* __restrict__ smOut) {
    const int b = blockIdx.y;
    const int n0 = blockIdx.x * 64;
    const int t = threadIdx.x;
    const int lane = t & 63;
    const int wave = t >> 6;
    const int li = lane & 15;
    const int quad = lane >> 4;
    const int nu = unselN[b];
    if (nu == 0) return;

    __shared__ __align__(16) ushort s_qh[64 * 72];    // [q_local][64 c] pad 72
    __shared__ __align__(16) ushort s_ql[64 * 72];
    __shared__ unsigned s_best[64];
    __shared__ int s_last;

    const float th = threArr[b];
    const int p0 = n0 + wave * 16 + li;
    const float rp0 = rn[b * 4096 + p0];
    const float ng0 = (pooledM[b * 4096 + p0] >= th) ? 0.0f : -INFINITY;

    for (int qs0 = 0; qs0 < nu; qs0 += 64) {
        __syncthreads();   // iter>0: prior s_best reads done
        // gather 64 q rows (hi/lo) from plain-x bf16 inb (grp 4-7), rq prefolded; zero beyond nu
        for (int idx = t; idx < 512; idx += 256) {
            int q_l = idx >> 3;          // 0..63
            int part = idx & 7;          // grp = 4 + (part>>1), sub = (part&1)*8
            int qg = qs0 + q_l;
            int q = 0;
            float rq = 0.0f;
            if (qg < nu) {
                q = unsel[b * 4096 + qg];
                rq = rn[b * 4096 + q];
            }
            uint4 raw = *(const uint4*)(inb + (((size_t)(b * 8 + 4 + (part >> 1)) * 4096) + q) * 16 + (part & 1) * 8);
            ushort hv[8]; *(uint4*)hv = raw;
            ushort hh[8], ll[8];
#pragma unroll
            for (int j = 0; j < 8; ++j) {
                float v = bf2f(hv[j]) * rq;
                hh[j] = f2bf(v);
                ll[j] = f2bf(v - bf2f(hh[j]));
            }
            int c0 = (part >> 1) * 16 + (part & 1) * 8;
            *(uint4*)(s_qh + q_l * 72 + c0) = *(const uint4*)hh;
            *(uint4*)(s_ql + q_l * 72 + c0) = *(const uint4*)ll;
        }
        if (t < 64) s_best[t] = 0u;
        __syncthreads();

        f32x4 acc[4];
#pragma unroll
        for (int mt = 0; mt < 4; ++mt) acc[mt] = (f32x4){0.f, 0.f, 0.f, 0.f};
#pragma unroll
        for (int k0 = 0; k0 < 2; ++k0) {
            const int cb = k0 * 32 + quad * 8;
            const int grp = 4 + (cb >> 4);
            const int sub = cb & 15;
            short8 b0 = *(const short8*)(inb + (((size_t)(b * 8 + grp) * 4096) + p0) * 16 + sub);
#pragma unroll
            for (int mt = 0; mt < 4; ++mt) {
                short8 ah = *(const short8*)(s_qh + (size_t)(mt * 16 + li) * 72 + cb);
                short8 al = *(const short8*)(s_ql + (size_t)(mt * 16 + li) * 72 + cb);
                acc[mt] = __builtin_amdgcn_mfma_f32_16x16x32_bf16(ah, b0, acc[mt], 0, 0, 0);
                acc[mt] = __builtin_amdgcn_mfma_f32_16x16x32_bf16(al, b0, acc[mt], 0, 0, 0);
            }
        }
        // epilogue: mask + scale, reduce max over the 16 p-lanes, scoreboard per q
#pragma unroll
        for (int mt = 0; mt < 4; ++mt) {
#pragma unroll
            for (int r = 0; r < 4; ++r) {
                float sc = acc[mt][r] * rp0 + ng0;
                sc = fmaxf(sc, __shfl_xor(sc, 1));
                sc = fmaxf(sc, __shfl_xor(sc, 2));
                sc = fmaxf(sc, __shfl_xor(sc, 4));
                sc = fmaxf(sc, __shfl_xor(sc, 8));
                if (li == 0) atomicMax(&s_best[mt * 16 + quad * 4 + r], mapf(sc));
            }
        }
        __syncthreads();
        if (t < 64 && qs0 + t < nu) atomicMax(scores + b * 4096 + qs0 + t, s_best[t]);
    }
    // ---- last-block-per-batch fixup ----
    __threadfence();                         // make this block's score atomics globally visible
    if (t == 0) s_last = (atomicAdd(&scoreDone[b], 1) == 63);
    __syncthreads();
    if (s_last) {
        for (int idx = t; idx < nu * 4; idx += 256) {
            int qi = idx >> 2;
            int part = idx & 3;              // channel grp of 16
            int q = unsel[b * 4096 + qi];
            float sm = unmapf(atomicOr(&scores[b * 4096 + qi], 0u)) * 0.5f + 0.5f;
            if (part == 0) smOut[b * 4096 + q] = sm;
            const ushort* src = inb + ((size_t)(b * 8 + 4 + part) * 4096 + q) * 16;  // plain copy
            ushort* dst = inb + ((size_t)(b * 8 + part) * 4096 + q) * 16;            // scaled copy
            ushort hv[16];
            *(uint4*)hv       = *(const uint4*)src;
            *(uint4*)(hv + 8) = *(const uint4*)(src + 8);
#pragma unroll
            for (int j = 0; j < 16; ++j) hv[j] = f2bf(bf2f(hv[j]) * sm);
            *(uint4*)dst       = *(const uint4*)hv;
            *(uint4*)(dst + 8) = *(const uint4*)(hv + 8);
        }
    }
}

// ---------------- K3: MFMA implicit-GEMM conv 3x3 (128->64) + bias + GN partials ----------------
// grid (32 rowblk, 4 ocblk, 4 b) = 512 blocks (2/CU), 256 thr = 4 waves.
// Wave = 16 oc x 32 w of one output row (2 C-tiles). Weights staged in LDS per 32-ic chunk;
// input B-fragments read DIRECTLY from global bf16 inb (coalesced 16B/lane, cndmask zero at borders).
__global__ __launch_bounds__(256) void k_conv_mfma(
    const ushort* __restrict__ inb, const ushort* __restrict__ wbh, const ushort* __restrict__ wbl,
    const float* __restrict__ bfuse, float* __restrict__ y,
    float* __restrict__ gnS1, float* __restrict__ gnS2) {
    const int rowblk = blockIdx.x;
    const int ocblk = blockIdx.y;
    const int b = blockIdx.z;
    const int t = threadIdx.x;
    const int lane = t & 63;
    const int wave = t >> 6;
    const int li = lane & 15;
    const int quad = lane >> 4;
    const int oc0 = ocblk * 16;
    const int hr = rowblk * 2 + (wave >> 1);   // this wave's output row
    const int j0 = (wave & 1) * 2;             // first of 2 col-tiles

    __shared__ __align__(16) ushort s_wh[9 * 16 * 40];   // [tap][oc][32ic pad40]
    __shared__ __align__(16) ushort s_wl[9 * 16 * 40];
    __shared__ float red1[256];
    __shared__ float red2[256];

    const short8 zero8 = (short8){0, 0, 0, 0, 0, 0, 0, 0};
    f32x4 acc[2];
    acc[0] = (f32x4){0.f, 0.f, 0.f, 0.f};
    acc[1] = (f32x4){0.f, 0.f, 0.f, 0.f};

    for (int chunk = 0; chunk < 4; ++chunk) {
        __syncthreads();
        // stage weights: {hi,lo} x 9 taps x 16 oc x 32 ic
        const int ic0 = chunk * 32;
        for (int idx = t; idx < 1152; idx += 256) {
            int part = idx & 3;
            int uu = idx >> 2;              // hl*144 + tap*16 + o
            int hl = uu / 144;
            int rem = uu - hl * 144;
            int tap = rem >> 4;
            int o = rem & 15;
            uint4 v = *(const uint4*)((hl ? wbl : wbh) + ((size_t)(tap * 64 + oc0 + o) * 128 + ic0 + part * 8));
            *(uint4*)((hl ? s_wl : s_wh) + ((size_t)(tap * 16 + o) * 40 + part * 8)) = v;
        }
        __syncthreads();
        // B base for this wave's quad: grp = 2*chunk + (quad>>1)  (chunks 0,1 -> scaled grps 0-3; 2,3 -> plain 4-7)
        const ushort* bbase = inb + ((size_t)(b * 8 + 2 * chunk + (quad >> 1)) * 4096) * 16 + (quad & 1) * 8;
#pragma unroll
        for (int kh = 0; kh < 3; ++kh) {
            const int r = hr + kh - 1;
            const bool rok = (unsigned)r < 64u;
            const int rbase = (rok ? r : 0) * 64;
#pragma unroll
            for (int kw = 0; kw < 3; ++kw) {
                const int tap = kh * 3 + kw;
                short8 ah = *(const short8*)(s_wh + (size_t)(tap * 16 + li) * 40 + quad * 8);
                short8 al = *(const short8*)(s_wl + (size_t)(tap * 16 + li) * 40 + quad * 8);
#pragma unroll
                for (int jj = 0; jj < 2; ++jj) {
                    const int w = (j0 + jj) * 16 + li + kw - 1;
                    const bool ok = rok && ((unsigned)w < 64u);
                    const int sp = rbase + (ok ? w : 0);
                    short8 bv = *(const short8*)(bbase + (size_t)sp * 16);
                    bv = ok ? bv : zero8;
                    acc[jj] = __builtin_amdgcn_mfma_f32_16x16x32_bf16(ah, bv, acc[jj], 0, 0, 0);
                    acc[jj] = __builtin_amdgcn_mfma_f32_16x16x32_bf16(al, bv, acc[jj], 0, 0, 0);
                }
            }
        }
    }
    // epilogue: bias, store (coalesced: li is w within tile), GN partial sums
    float s1 = 0.f, s2 = 0.f;
#pragma unroll
    for (int jj = 0; jj < 2; ++jj) {
#pragma unroll
        for (int reg = 0; reg < 4; ++reg) {
            float v = acc[jj][reg] + bfuse[oc0 + quad * 4 + reg];
            y[((size_t)(b * 64 + oc0 + quad * 4 + reg)) * HW + hr * 64 + (j0 + jj) * 16 + li] = v;
            s1 += v; s2 += v * v;
        }
    }
    red1[t] = s1; red2[t] = s2;
    __syncthreads();
    for (int s = 128; s > 0; s >>= 1) {
        if (t < s) { red1[t] += red1[t + s]; red2[t] += red2[t + s]; }
        __syncthreads();
    }
    if (t == 0) {
        atomicAdd(&gnS1[b], red1[0]);
        atomicAdd(&gnS2[b], red2[0]);
    }
}

// ---------------- K4: GroupNorm(1 group) + affine + ReLU, in-place on out ----------------
__global__ void k_gn(float* __restrict__ out, const float* __restrict__ gnS1, const float* __restrict__ gnS2,
                     const float* __restrict__ gamma, const float* __restrict__ beta) {
    const int e = (blockIdx.x * 256 + threadIdx.x) * 4;
    const int b = e >> 18;
    const int c = (e >> 12) & 63;
    const float inv = 1.0f / 262144.0f;
    float mu = gnS1[b] * inv;
    float var = gnS2[b] * inv - mu * mu;
    float rs = rsqrtf(var + 1e-5f);
    float scale = rs * gamma[c];
    float shift = beta[c] - mu * scale;
    float4 v = *(const float4*)(out + e);
    float4 o;
    o.x = fmaxf(v.x * scale + shift, 0.0f);
    o.y = fmaxf(v.y * scale + shift, 0.0f);
    o.z = fmaxf(v.z * scale + shift, 0.0f);
    o.w = fmaxf(v.w * scale + shift, 0.0f);
    *(float4*)(out + e) = o;
}

extern "C" void kernel_launch(void* const* d_in, const int* in_sizes, int n_in,
                              void* d_out, int out_size, void* d_ws, size_t ws_size,
                              hipStream_t stream) {
    const float* fdm   = (const float*)d_in[0];
    const float* x     = (const float*)d_in[1];
    const float* Wf    = (const float*)d_in[2];
    const float* bfuse = (const float*)d_in[3];
    const float* gamma = (const float*)d_in[4];
    const float* beta  = (const float*)d_in[5];
    float* out = (float*)d_out;
    float* ws  = (float*)d_ws;

    // workspace layout (float offsets, all 16B-aligned)
    float*    rn       = ws;                          // 16384
    float*    pooledM  = rn + 16384;                  // 16384
    int*      unsel    = (int*)(pooledM + 16384);     // 16384
    unsigned* scores   = (unsigned*)(unsel + 16384);  // 16384
    float*    thre     = (float*)(scores + 16384);    // 4
    int*      unselN   = (int*)(thre + 4);            // 4
    float*    gnS1     = (float*)(unselN + 4);        // 4
    float*    gnS2     = gnS1 + 4;                    // 4
    int*      scoreDone= (int*)(gnS2 + 4);            // 4
    ushort*   wbh      = (ushort*)(scoreDone + 4);    // 73728 halves
    ushort*   wbl      = wbh + 73728;                 // 73728 halves
    ushort*   inb      = wbl + 73728;                 // 4194304 halves (8 MB, two copies)

    float* yout  = out;                               // conv output in out[0..1M), GN in-place
    float* smOut = out + 1048576;                     // second output

    k_pnp<<<dim3(296), dim3(256), 0, stream>>>(fdm, x, Wf, pooledM, thre, unsel, unselN,
                                               scores, scoreDone, gnS1, gnS2, rn, smOut, inb, wbh, wbl);
    k_score<<<dim3(64, 4), dim3(256), 0, stream>>>(rn, pooledM, thre, unsel, unselN,
                                                   inb, scores, scoreDone, smOut);
    k_conv_mfma<<<dim3(32, 4, 4), dim3(256), 0, stream>>>(inb, wbh, wbl, bfuse, yout, gnS1, gnS2);
    k_gn<<<dim3(1024), dim3(256), 0, stream>>>(yout, gnS1, gnS2, gamma, beta);
}

// Round 10
// 117.310 us; speedup vs baseline: 1.0863x; 1.0863x over previous
//
#include <hip/hip_runtime.h>
#include <math.h>

// Problem constants: b=4, f=64, h=w=64, HW=4096
// Inputs: fdm [4,1,128,128], x [4,64,64,64], W_fuse [64,128,3,3], b_fuse [64], gamma [64], beta [64]
// Outputs concatenated: x0 [4,64,64,64] (1048576 f32) then sm [4,1,64,64] (16384 f32)

#define HW 4096
#define NCH 64

typedef __attribute__((ext_vector_type(8))) short short8;
typedef __attribute__((ext_vector_type(4))) float f32x4;

static __device__ __forceinline__ ushort f2bf(float f) {
    unsigned u = __float_as_uint(f);
    unsigned r = (u + 0x7fffu + ((u >> 16) & 1u)) >> 16;   // RNE
    return (ushort)r;
}
static __device__ __forceinline__ float bf2f(ushort h) {
    return __uint_as_float(((unsigned)h) << 16);
}
// order-preserving float <-> uint map for atomicMax
static __device__ __forceinline__ unsigned mapf(float f) {
    unsigned u = __float_as_uint(f);
    return u ^ ((unsigned)((int)u >> 31) | 0x80000000u);
}
static __device__ __forceinline__ float unmapf(unsigned u) {
    unsigned b = (u & 0x80000000u) ? (u ^ 0x80000000u) : ~u;
    return __uint_as_float(b);
}

// ---------------- K1: pool (blk 0-3) || norm+bf16-prep (blk 4-259) || weight-prep (blk 260-295) ----------------
// inb layout: [b][8 grp][sp 4096][16 halves]; grp 0-3 = sm*x ch {0..63}, grp 4-7 = x ch {0..63}.
// Both halves written with scale=1; conv rescales the ~50 unselected cells in LDS.
__global__ __launch_bounds__(256) void k_pnp(
    const float* __restrict__ fdm, const float* __restrict__ x, const float* __restrict__ W,
    float* __restrict__ pooledOut, float* __restrict__ threOut,
    int* __restrict__ unsel, int* __restrict__ unselN, unsigned* __restrict__ scores,
    float* __restrict__ gnS1, float* __restrict__ gnS2,
    float* __restrict__ rn, float* __restrict__ smOut, ushort* __restrict__ inb,
    ushort* __restrict__ wbh, ushort* __restrict__ wbl) {
    const int t = threadIdx.x;
    if (blockIdx.x < 4) {
        // ---- pool path ----
        const int b = blockIdx.x;
        __shared__ float pooled[4096];
        __shared__ float red[256];
        __shared__ int cnt;
        const float* fb = fdm + b * 16384;
        float lmax = -1.0f;
#pragma unroll
        for (int it = 0; it < 8; ++it) {
            int id2 = it * 256 + t;
            int i = id2 >> 5;
            int j2 = id2 & 31;
            const float* base = fb + i * 256 + j2 * 4;
            float4 a = *(const float4*)base;
            float4 c = *(const float4*)(base + 128);
            float p0 = fmaxf(fmaxf(a.x, a.y), fmaxf(c.x, c.y));
            float p1 = fmaxf(fmaxf(a.z, a.w), fmaxf(c.z, c.w));
            pooled[i * 64 + j2 * 2]     = p0;
            pooled[i * 64 + j2 * 2 + 1] = p1;
            lmax = fmaxf(lmax, fmaxf(p0, p1));
        }
        red[t] = lmax;
        __syncthreads();
        for (int s = 128; s > 0; s >>= 1) {
            if (t < s) red[t] = fmaxf(red[t], red[t + s]);
            __syncthreads();
        }
        __shared__ float thre_s;
        if (t == 0) {
            thre_s = fminf(0.5f, red[0] / 3.0f);   // exact reference fp32 rounding
            cnt = 0;
            gnS1[b] = 0.0f; gnS2[b] = 0.0f;
        }
        __syncthreads();
        const float th = thre_s;
#pragma unroll
        for (int it = 0; it < 4; ++it) {
            int idx = (it * 256 + t) * 4;
            *(float4*)(pooledOut + b * 4096 + idx) = *(const float4*)(pooled + idx);
        }
        for (int idx = t; idx < 4096; idx += 256) {
            scores[b * 4096 + idx] = 0u;           // zero-init scoreboard (ws is poisoned)
            if (!(pooled[idx] >= th)) {
                int pos = atomicAdd(&cnt, 1);
                unsel[b * 4096 + pos] = idx;
            }
        }
        __syncthreads();
        if (t == 0) { unselN[b] = cnt; threOut[b] = th; }
    } else if (blockIdx.x < 260) {
        // ---- norm + prep path ----
        __shared__ float s_part[4][64];
        const int n = blockIdx.x - 4;       // 0..255
        const int b = n >> 6;
        const int pbase = (n & 63) * 64;
        const int wv = t >> 6;              // channel group of 16
        const int l = t & 63;               // position within 64-slice
        const int sp = pbase + l;
        const float* xp = x + b * (NCH * HW) + sp;
        float xv[16];
        float ss = 0.f;
#pragma unroll
        for (int i = 0; i < 16; ++i) {
            float a = xp[(wv * 16 + i) * HW];
            xv[i] = a;
            ss += a * a;
        }
        s_part[wv][l] = ss;
        ushort h[16];
#pragma unroll
        for (int i = 0; i < 16; ++i) h[i] = f2bf(xv[i]);
        size_t dst1 = ((size_t)(b * 8 + wv) * 4096 + sp) * 16;
        size_t dst2 = ((size_t)(b * 8 + 4 + wv) * 4096 + sp) * 16;
        *(uint4*)(inb + dst1)     = *(const uint4*)h;
        *(uint4*)(inb + dst1 + 8) = *(const uint4*)(h + 8);
        *(uint4*)(inb + dst2)     = *(const uint4*)h;
        *(uint4*)(inb + dst2 + 8) = *(const uint4*)(h + 8);
        __syncthreads();
        if (t < 64) {
            float s = s_part[0][l] + s_part[1][l] + s_part[2][l] + s_part[3][l];
            int g = b * HW + pbase + l;
            rn[g] = 1.0f / fmaxf(sqrtf(s), 1e-8f);
            smOut[g] = 1.0f;
        }
    } else {
        // ---- weight prep: bf16 hi/lo, layout [tap][oc][ic128] ----
        const int u = (blockIdx.x - 260) * 256 + t;   // 0..9215 = tap*1024 + oc*16 + g
        const int tap = u >> 10;
        const int rem = u & 1023;
        const int oc = rem >> 4;
        const int g = rem & 15;
        ushort hh[8], ll[8];
#pragma unroll
        for (int j = 0; j < 8; ++j) {
            int ic = g * 8 + j;
            float v = W[(oc * 128 + ic) * 9 + tap];
            ushort hb = f2bf(v);
            hh[j] = hb;
            ll[j] = f2bf(v - bf2f(hb));
        }
        *(uint4*)(wbh + (size_t)u * 8) = *(const uint4*)hh;
        *(uint4*)(wbl + (size_t)u * 8) = *(const uint4*)ll;
    }
}

// ---------------- K2: score via MFMA — D[q,p] = q_hat . x_p, masked max over p ----------------
// grid (32 p-strips, 4 b), 256 threads = 4 waves. Strip = 128 p, wave covers 32 p (2 n-tiles).
// A = q_hat hi/lo gathered into LDS from x (rq prefolded); B = x bf16 read DIRECTLY from inb (global).
__global__ __launch_bounds__(256) void k_score(
    const float* __restrict__ x, const float* __restrict__ rn,
    const float* __restrict__ pooledM, const float* __restrict__ threArr,
    const int* __restrict__ unsel, const int* __restrict__ unselN,
    const ushort* __restrict__ inb, unsigned* __restrict__ scores) {
    const int b = blockIdx.y;
    const int n0 = blockIdx.x * 128;
    const int t = threadIdx.x;
    const int lane = t & 63;
    const int wave = t >> 6;
    const int li = lane & 15;
    const int quad = lane >> 4;
    const int nu = unselN[b];
    if (nu == 0) return;

    __shared__ __align__(16) ushort s_qh[64 * 72];    // [q_local][64 c] pad 72
    __shared__ __align__(16) ushort s_ql[64 * 72];
    __shared__ unsigned s_best[64];

    const float th = threArr[b];
    const int p0 = n0 + (2 * wave) * 16 + li;
    const int p1 = n0 + (2 * wave + 1) * 16 + li;
    const float rp0 = rn[b * 4096 + p0];
    const float rp1 = rn[b * 4096 + p1];
    const float ng0 = (pooledM[b * 4096 + p0] >= th) ? 0.0f : -INFINITY;
    const float ng1 = (pooledM[b * 4096 + p1] >= th) ? 0.0f : -INFINITY;

    for (int qs0 = 0; qs0 < nu; qs0 += 64) {
        __syncthreads();   // iter>0: prior s_best reads done
        // gather 64 q rows (hi/lo) from x, rq prefolded; zero-pad beyond nu
        for (int idx = t; idx < 4096; idx += 256) {
            int q_l = idx >> 6;
            int c = idx & 63;
            int qg = qs0 + q_l;
            float v = 0.0f;
            if (qg < nu) {
                int q = unsel[b * 4096 + qg];
                v = x[b * (NCH * HW) + c * HW + q] * rn[b * 4096 + q];
            }
            ushort hb = f2bf(v);
            s_qh[q_l * 72 + c] = hb;
            s_ql[q_l * 72 + c] = f2bf(v - bf2f(hb));
        }
        if (t < 64) s_best[t] = 0u;
        __syncthreads();

        f32x4 acc[2][4];
#pragma unroll
        for (int nt = 0; nt < 2; ++nt)
#pragma unroll
            for (int mt = 0; mt < 4; ++mt) acc[nt][mt] = (f32x4){0.f, 0.f, 0.f, 0.f};
#pragma unroll
        for (int k0 = 0; k0 < 2; ++k0) {
            const int cb = k0 * 32 + quad * 8;
            const int grp = 4 + (cb >> 4);
            const int sub = cb & 15;
            short8 b0 = *(const short8*)(inb + (((size_t)(b * 8 + grp) * 4096) + p0) * 16 + sub);
            short8 b1 = *(const short8*)(inb + (((size_t)(b * 8 + grp) * 4096) + p1) * 16 + sub);
#pragma unroll
            for (int mt = 0; mt < 4; ++mt) {
                short8 ah = *(const short8*)(s_qh + (size_t)(mt * 16 + li) * 72 + cb);
                short8 al = *(const short8*)(s_ql + (size_t)(mt * 16 + li) * 72 + cb);
                acc[0][mt] = __builtin_amdgcn_mfma_f32_16x16x32_bf16(ah, b0, acc[0][mt], 0, 0, 0);
                acc[0][mt] = __builtin_amdgcn_mfma_f32_16x16x32_bf16(al, b0, acc[0][mt], 0, 0, 0);
                acc[1][mt] = __builtin_amdgcn_mfma_f32_16x16x32_bf16(ah, b1, acc[1][mt], 0, 0, 0);
                acc[1][mt] = __builtin_amdgcn_mfma_f32_16x16x32_bf16(al, b1, acc[1][mt], 0, 0, 0);
            }
        }
        // epilogue: mask + scale, reduce max over the 16 p-lanes, scoreboard per q
#pragma unroll
        for (int mt = 0; mt < 4; ++mt) {
#pragma unroll
            for (int r = 0; r < 4; ++r) {
                float sc = fmaxf(acc[0][mt][r] * rp0 + ng0, acc[1][mt][r] * rp1 + ng1);
                sc = fmaxf(sc, __shfl_xor(sc, 1));
                sc = fmaxf(sc, __shfl_xor(sc, 2));
                sc = fmaxf(sc, __shfl_xor(sc, 4));
                sc = fmaxf(sc, __shfl_xor(sc, 8));
                if (li == 0) atomicMax(&s_best[mt * 16 + quad * 4 + r], mapf(sc));
            }
        }
        __syncthreads();
        if (t < 64 && qs0 + t < nu) atomicMax(scores + b * 4096 + qs0 + t, s_best[t]);
    }
}

// ---------------- K3: MFMA implicit-GEMM conv 3x3 (128->64) + in-LDS sm fixup + bias + GN partials ----------------
// grid (32 rowblk, 4 ocblk, 4 b) = 512 blocks (2/CU — the R10 occupancy fix), block 256 = 4 waves.
// Block computes 16 oc x 2 rows x 64 w; wave = 1 row x 32 w (2 C-tiles). LDS ~46 KB.
__global__ __launch_bounds__(256) void k_conv_mfma(
    const ushort* __restrict__ inb, const ushort* __restrict__ wbh, const ushort* __restrict__ wbl,
    const float* __restrict__ bfuse, const int* __restrict__ unsel, const int* __restrict__ unselN,
    const unsigned* __restrict__ scores, float* __restrict__ smOut,
    float* __restrict__ y, float* __restrict__ gnS1, float* __restrict__ gnS2) {
    const int rowblk = blockIdx.x;
    const int ocblk = blockIdx.y;
    const int b = blockIdx.z;
    const int t = threadIdx.x;
    const int lane = t & 63;
    const int wave = t >> 6;
    const int li = lane & 15;
    const int quad = lane >> 4;
    const int h0 = rowblk * 2;
    const int oc0 = ocblk * 16;
    const int nu = unselN[b];

    __shared__ __align__(16) ushort s_in[4 * 66 * 40];   // [r 4][c 66][32ic pad40] halves (~21 KB)
    __shared__ __align__(16) ushort s_wh[9 * 16 * 40];   // [tap][oc][32ic pad40] (~11 KB)
    __shared__ __align__(16) ushort s_wl[9 * 16 * 40];
    __shared__ float red1[256];
    __shared__ float red2[256];

    // designated block per batch finalizes the sm output for unselected q
    if (rowblk == 0 && ocblk == 0) {
        for (int qi = t; qi < nu; qi += 256) {
            float sm = unmapf(scores[b * 4096 + qi]) * 0.5f + 0.5f;
            smOut[b * 4096 + unsel[b * 4096 + qi]] = sm;
        }
    }

    f32x4 acc[2];
    acc[0] = (f32x4){0.f, 0.f, 0.f, 0.f};
    acc[1] = (f32x4){0.f, 0.f, 0.f, 0.f};

    for (int chunk = 0; chunk < 4; ++chunk) {
        __syncthreads();
        // stage input slab: rows h0-1..h0+2 (4), cols -1..64 (66), 32 ic (4 x 16B parts per cell)
        // inb layout: [b][8 grp][sp][16 halves]; chunk c covers grps {2c, 2c+1}
        for (int idx = t; idx < 1056; idx += 256) {
            int part = idx & 3;
            int cell = idx >> 2;
            int r = cell / 66;
            int c = cell - r * 66;
            int h = h0 + r - 1;
            int w = c - 1;
            uint4 v = make_uint4(0u, 0u, 0u, 0u);
            if ((unsigned)h < 64u && (unsigned)w < 64u) {
                int grp = 2 * chunk + (part >> 1);
                int sub = part & 1;
                v = *(const uint4*)(inb + (((size_t)(b * 8 + grp) * 4096 + h * 64 + w) * 16 + sub * 8));
            }
            *(uint4*)(s_in + (size_t)cell * 40 + part * 8) = v;
        }
        // stage weights: {hi,lo} x 9 taps x 16 oc x 4 parts
        const int ic0 = chunk * 32;
        for (int idx = t; idx < 1152; idx += 256) {
            int part = idx & 3;
            int uu = idx >> 2;              // hl*144 + tap*16 + o
            int hl = uu / 144;
            int rem = uu - hl * 144;
            int tap = rem >> 4;
            int o = rem & 15;
            uint4 v = *(const uint4*)((hl ? wbl : wbh) + ((size_t)(tap * 64 + oc0 + o) * 128 + ic0 + part * 8));
            *(uint4*)((hl ? s_wl : s_wh) + ((size_t)(tap * 16 + o) * 40 + part * 8)) = v;
        }
        // in-LDS sm rescale of unselected positions (scaled half = chunks 0,1 only)
        if (chunk < 2) {
            __syncthreads();   // staging visible before modification
            for (int idx = t; idx < nu * 4; idx += 256) {
                int qi = idx >> 2;
                int part = idx & 3;
                int q = unsel[b * 4096 + qi];
                int hq = q >> 6, wq = q & 63;
                int r = hq - h0 + 1;
                if ((unsigned)r < 4u) {
                    float sm = unmapf(scores[b * 4096 + qi]) * 0.5f + 0.5f;
                    ushort* ptr = s_in + (size_t)(r * 66 + wq + 1) * 40 + part * 8;
                    ushort hv[8];
                    *(uint4*)hv = *(const uint4*)ptr;
#pragma unroll
                    for (int j = 0; j < 8; ++j) hv[j] = f2bf(bf2f(hv[j]) * sm);
                    *(uint4*)ptr = *(const uint4*)hv;
                }
            }
        }
        __syncthreads();
        const int r0 = wave >> 1;           // this wave's output row within block (0/1)
        const int j0 = (wave & 1) * 2;      // first of 2 col-tiles
#pragma unroll
        for (int kh = 0; kh < 3; ++kh) {
            const int r = r0 + kh;
#pragma unroll
            for (int kw = 0; kw < 3; ++kw) {
                const int tap = kh * 3 + kw;
                short8 ah = *(const short8*)(s_wh + (size_t)(tap * 16 + li) * 40 + quad * 8);
                short8 al = *(const short8*)(s_wl + (size_t)(tap * 16 + li) * 40 + quad * 8);
#pragma unroll
                for (int jj = 0; jj < 2; ++jj) {
                    int c = (j0 + jj) * 16 + li + kw;
                    short8 bv = *(const short8*)(s_in + ((size_t)(r * 66 + c) * 40 + quad * 8));
                    acc[jj] = __builtin_amdgcn_mfma_f32_16x16x32_bf16(ah, bv, acc[jj], 0, 0, 0);
                    acc[jj] = __builtin_amdgcn_mfma_f32_16x16x32_bf16(al, bv, acc[jj], 0, 0, 0);
                }
            }
        }
    }
    // epilogue: bias, store (coalesced: li is w within tile), GN partial sums
    const int hrow = h0 + (wave >> 1);
    const int j0 = (wave & 1) * 2;
    float s1 = 0.f, s2 = 0.f;
#pragma unroll
    for (int jj = 0; jj < 2; ++jj) {
#pragma unroll
        for (int reg = 0; reg < 4; ++reg) {
            float v = acc[jj][reg] + bfuse[oc0 + quad * 4 + reg];
            y[((size_t)(b * 64 + oc0 + quad * 4 + reg)) * HW + hrow * 64 + (j0 + jj) * 16 + li] = v;
            s1 += v; s2 += v * v;
        }
    }
    red1[t] = s1; red2[t] = s2;
    __syncthreads();
    for (int s = 128; s > 0; s >>= 1) {
        if (t < s) { red1[t] += red1[t + s]; red2[t] += red2[t + s]; }
        __syncthreads();
    }
    if (t == 0) {
        atomicAdd(&gnS1[b], red1[0]);
        atomicAdd(&gnS2[b], red2[0]);
    }
}

// ---------------- K4: GroupNorm(1 group) + affine + ReLU, in-place on out ----------------
__global__ void k_gn(float* __restrict__ out, const float* __restrict__ gnS1, const float* __restrict__ gnS2,
                     const float* __restrict__ gamma, const float* __restrict__ beta) {
    const int e = (blockIdx.x * 256 + threadIdx.x) * 4;
    const int b = e >> 18;
    const int c = (e >> 12) & 63;
    const float inv = 1.0f / 262144.0f;
    float mu = gnS1[b] * inv;
    float var = gnS2[b] * inv - mu * mu;
    float rs = rsqrtf(var + 1e-5f);
    float scale = rs * gamma[c];
    float shift = beta[c] - mu * scale;
    float4 v = *(const float4*)(out + e);
    float4 o;
    o.x = fmaxf(v.x * scale + shift, 0.0f);
    o.y = fmaxf(v.y * scale + shift, 0.0f);
    o.z = fmaxf(v.z * scale + shift, 0.0f);
    o.w = fmaxf(v.w * scale + shift, 0.0f);
    *(float4*)(out + e) = o;
}

extern "C" void kernel_launch(void* const* d_in, const int* in_sizes, int n_in,
                              void* d_out, int out_size, void* d_ws, size_t ws_size,
                              hipStream_t stream) {
    const float* fdm   = (const float*)d_in[0];
    const float* x     = (const float*)d_in[1];
    const float* Wf    = (const float*)d_in[2];
    const float* bfuse = (const float*)d_in[3];
    const float* gamma = (const float*)d_in[4];
    const float* beta  = (const float*)d_in[5];
    float* out = (float*)d_out;
    float* ws  = (float*)d_ws;

    // workspace layout (float offsets, all 16B-aligned)
    float*    rn      = ws;                         // 16384
    float*    pooledM = rn + 16384;                 // 16384
    int*      unsel   = (int*)(pooledM + 16384);    // 16384
    unsigned* scores  = (unsigned*)(unsel + 16384); // 16384
    float*    thre    = (float*)(scores + 16384);   // 4
    int*      unselN  = (int*)(thre + 4);           // 4
    float*    gnS1    = (float*)(unselN + 4);       // 4
    float*    gnS2    = gnS1 + 4;                   // 4
    ushort*   wbh     = (ushort*)(gnS2 + 4);        // 73728 halves
    ushort*   wbl     = wbh + 73728;                // 73728 halves
    ushort*   inb     = wbl + 73728;                // 4194304 halves (8 MB)

    float* yout  = out;                             // conv output in out[0..1M), GN in-place
    float* smOut = out + 1048576;                   // second output

    k_pnp<<<dim3(296), dim3(256), 0, stream>>>(fdm, x, Wf, pooledM, thre, unsel, unselN,
                                               scores, gnS1, gnS2, rn, smOut, inb, wbh, wbl);
    k_score<<<dim3(32, 4), dim3(256), 0, stream>>>(x, rn, pooledM, thre, unsel, unselN, inb, scores);
    k_conv_mfma<<<dim3(32, 4, 4), dim3(256), 0, stream>>>(inb, wbh, wbl, bfuse, unsel, unselN,
                                                          scores, smOut, yout, gnS1, gnS2);
    k_gn<<<dim3(1024), dim3(256), 0, stream>>>(yout, gnS1, gnS2, gamma, beta);
}

// Round 11
// 106.855 us; speedup vs baseline: 1.1926x; 1.0979x over previous
//
#include <hip/hip_runtime.h>
#include <math.h>

// Problem constants: b=4, f=64, h=w=64, HW=4096
// Inputs: fdm [4,1,128,128], x [4,64,64,64], W_fuse [64,128,3,3], b_fuse [64], gamma [64], beta [64]
// Outputs concatenated: x0 [4,64,64,64] (1048576 f32) then sm [4,1,64,64] (16384 f32)

#define HW 4096
#define NCH 64

typedef __attribute__((ext_vector_type(8))) short short8;
typedef __attribute__((ext_vector_type(4))) float f32x4;

static __device__ __forceinline__ ushort f2bf(float f) {
    unsigned u = __float_as_uint(f);
    unsigned r = (u + 0x7fffu + ((u >> 16) & 1u)) >> 16;   // RNE
    return (ushort)r;
}
static __device__ __forceinline__ float bf2f(ushort h) {
    return __uint_as_float(((unsigned)h) << 16);
}
// order-preserving float <-> uint map for atomicMax
static __device__ __forceinline__ unsigned mapf(float f) {
    unsigned u = __float_as_uint(f);
    return u ^ ((unsigned)((int)u >> 31) | 0x80000000u);
}
static __device__ __forceinline__ float unmapf(unsigned u) {
    unsigned b = (u & 0x80000000u) ? (u ^ 0x80000000u) : ~u;
    return __uint_as_float(b);
}

// ---------------- K1: pool (blk 0-3) || norm+bf16-prep (blk 4-259) || weight-prep (blk 260-295) ----------------
// inb layout: [b][8 grp][sp 4096][16 halves]; grp 0-3 = sm*x ch {0..63}, grp 4-7 = x ch {0..63}.
// Both halves written with scale=1; conv rescales the ~50 unselected cells in LDS.
__global__ __launch_bounds__(256) void k_pnp(
    const float* __restrict__ fdm, const float* __restrict__ x, const float* __restrict__ W,
    float* __restrict__ pooledOut, float* __restrict__ threOut,
    int* __restrict__ unsel, int* __restrict__ unselN, unsigned* __restrict__ scores,
    float* __restrict__ gnS1, float* __restrict__ gnS2,
    float* __restrict__ rn, float* __restrict__ smOut, ushort* __restrict__ inb,
    ushort* __restrict__ wbh, ushort* __restrict__ wbl) {
    const int t = threadIdx.x;
    if (blockIdx.x < 4) {
        // ---- pool path ----
        const int b = blockIdx.x;
        __shared__ float pooled[4096];
        __shared__ float red[256];
        __shared__ int cnt;
        const float* fb = fdm + b * 16384;
        float lmax = -1.0f;
#pragma unroll
        for (int it = 0; it < 8; ++it) {
            int id2 = it * 256 + t;
            int i = id2 >> 5;
            int j2 = id2 & 31;
            const float* base = fb + i * 256 + j2 * 4;
            float4 a = *(const float4*)base;
            float4 c = *(const float4*)(base + 128);
            float p0 = fmaxf(fmaxf(a.x, a.y), fmaxf(c.x, c.y));
            float p1 = fmaxf(fmaxf(a.z, a.w), fmaxf(c.z, c.w));
            pooled[i * 64 + j2 * 2]     = p0;
            pooled[i * 64 + j2 * 2 + 1] = p1;
            lmax = fmaxf(lmax, fmaxf(p0, p1));
        }
        red[t] = lmax;
        __syncthreads();
        for (int s = 128; s > 0; s >>= 1) {
            if (t < s) red[t] = fmaxf(red[t], red[t + s]);
            __syncthreads();
        }
        __shared__ float thre_s;
        if (t == 0) {
            thre_s = fminf(0.5f, red[0] / 3.0f);   // exact reference fp32 rounding
            cnt = 0;
            gnS1[b] = 0.0f; gnS2[b] = 0.0f;
        }
        __syncthreads();
        const float th = thre_s;
#pragma unroll
        for (int it = 0; it < 4; ++it) {
            int idx = (it * 256 + t) * 4;
            *(float4*)(pooledOut + b * 4096 + idx) = *(const float4*)(pooled + idx);
        }
        for (int idx = t; idx < 4096; idx += 256) {
            scores[b * 4096 + idx] = 0u;           // zero-init scoreboard (ws is poisoned)
            if (!(pooled[idx] >= th)) {
                int pos = atomicAdd(&cnt, 1);
                unsel[b * 4096 + pos] = idx;
            }
        }
        __syncthreads();
        if (t == 0) { unselN[b] = cnt; threOut[b] = th; }
    } else if (blockIdx.x < 260) {
        // ---- norm + prep path ----
        __shared__ float s_part[4][64];
        const int n = blockIdx.x - 4;       // 0..255
        const int b = n >> 6;
        const int pbase = (n & 63) * 64;
        const int wv = t >> 6;              // channel group of 16
        const int l = t & 63;               // position within 64-slice
        const int sp = pbase + l;
        const float* xp = x + b * (NCH * HW) + sp;
        float xv[16];
        float ss = 0.f;
#pragma unroll
        for (int i = 0; i < 16; ++i) {
            float a = xp[(wv * 16 + i) * HW];
            xv[i] = a;
            ss += a * a;
        }
        s_part[wv][l] = ss;
        ushort h[16];
#pragma unroll
        for (int i = 0; i < 16; ++i) h[i] = f2bf(xv[i]);
        size_t dst1 = ((size_t)(b * 8 + wv) * 4096 + sp) * 16;
        size_t dst2 = ((size_t)(b * 8 + 4 + wv) * 4096 + sp) * 16;
        *(uint4*)(inb + dst1)     = *(const uint4*)h;
        *(uint4*)(inb + dst1 + 8) = *(const uint4*)(h + 8);
        *(uint4*)(inb + dst2)     = *(const uint4*)h;
        *(uint4*)(inb + dst2 + 8) = *(const uint4*)(h + 8);
        __syncthreads();
        if (t < 64) {
            float s = s_part[0][l] + s_part[1][l] + s_part[2][l] + s_part[3][l];
            int g = b * HW + pbase + l;
            rn[g] = 1.0f / fmaxf(sqrtf(s), 1e-8f);
            smOut[g] = 1.0f;
        }
    } else {
        // ---- weight prep: bf16 hi/lo, layout [tap][oc][ic128] ----
        const int u = (blockIdx.x - 260) * 256 + t;   // 0..9215 = tap*1024 + oc*16 + g
        const int tap = u >> 10;
        const int rem = u & 1023;
        const int oc = rem >> 4;
        const int g = rem & 15;
        ushort hh[8], ll[8];
#pragma unroll
        for (int j = 0; j < 8; ++j) {
            int ic = g * 8 + j;
            float v = W[(oc * 128 + ic) * 9 + tap];
            ushort hb = f2bf(v);
            hh[j] = hb;
            ll[j] = f2bf(v - bf2f(hb));
        }
        *(uint4*)(wbh + (size_t)u * 8) = *(const uint4*)hh;
        *(uint4*)(wbl + (size_t)u * 8) = *(const uint4*)ll;
    }
}

// ---------------- K2: score via MFMA — D[q,p] = q_hat . x_p, masked max over p ----------------
// grid (32 p-strips, 4 b), 256 threads = 4 waves. Strip = 128 p, wave covers 32 p (2 n-tiles).
// A = q_hat hi/lo gathered into LDS from bf16 inb (rq prefolded, coalesced 16B loads — R8-validated);
// B = x bf16 read DIRECTLY from inb grp 4-7 (global).
__global__ __launch_bounds__(256) void k_score(
    const float* __restrict__ rn, const float* __restrict__ pooledM, const float* __restrict__ threArr,
    const int* __restrict__ unsel, const int* __restrict__ unselN,
    const ushort* __restrict__ inb, unsigned* __restrict__ scores) {
    const int b = blockIdx.y;
    const int n0 = blockIdx.x * 128;
    const int t = threadIdx.x;
    const int lane = t & 63;
    const int wave = t >> 6;
    const int li = lane & 15;
    const int quad = lane >> 4;
    const int nu = unselN[b];
    if (nu == 0) return;

    __shared__ __align__(16) ushort s_qh[64 * 72];    // [q_local][64 c] pad 72
    __shared__ __align__(16) ushort s_ql[64 * 72];
    __shared__ unsigned s_best[64];

    const float th = threArr[b];
    const int p0 = n0 + (2 * wave) * 16 + li;
    const int p1 = n0 + (2 * wave + 1) * 16 + li;
    const float rp0 = rn[b * 4096 + p0];
    const float rp1 = rn[b * 4096 + p1];
    const float ng0 = (pooledM[b * 4096 + p0] >= th) ? 0.0f : -INFINITY;
    const float ng1 = (pooledM[b * 4096 + p1] >= th) ? 0.0f : -INFINITY;

    for (int qs0 = 0; qs0 < nu; qs0 += 64) {
        __syncthreads();   // iter>0: prior s_best reads done
        // gather 64 q rows (hi/lo) from plain-x bf16 inb (grp 4-7), rq prefolded; zero beyond nu
        for (int idx = t; idx < 512; idx += 256) {
            int q_l = idx >> 3;          // 0..63
            int part = idx & 7;          // grp = 4 + (part>>1), sub = (part&1)*8
            int qg = qs0 + q_l;
            int q = 0;
            float rq = 0.0f;
            if (qg < nu) {
                q = unsel[b * 4096 + qg];
                rq = rn[b * 4096 + q];
            }
            uint4 raw = *(const uint4*)(inb + (((size_t)(b * 8 + 4 + (part >> 1)) * 4096) + q) * 16 + (part & 1) * 8);
            ushort hv[8]; *(uint4*)hv = raw;
            ushort hh[8], ll[8];
#pragma unroll
            for (int j = 0; j < 8; ++j) {
                float v = bf2f(hv[j]) * rq;
                hh[j] = f2bf(v);
                ll[j] = f2bf(v - bf2f(hh[j]));
            }
            int c0 = (part >> 1) * 16 + (part & 1) * 8;
            *(uint4*)(s_qh + q_l * 72 + c0) = *(const uint4*)hh;
            *(uint4*)(s_ql + q_l * 72 + c0) = *(const uint4*)ll;
        }
        if (t < 64) s_best[t] = 0u;
        __syncthreads();

        f32x4 acc[2][4];
#pragma unroll
        for (int nt = 0; nt < 2; ++nt)
#pragma unroll
            for (int mt = 0; mt < 4; ++mt) acc[nt][mt] = (f32x4){0.f, 0.f, 0.f, 0.f};
#pragma unroll
        for (int k0 = 0; k0 < 2; ++k0) {
            const int cb = k0 * 32 + quad * 8;
            const int grp = 4 + (cb >> 4);
            const int sub = cb & 15;
            short8 b0 = *(const short8*)(inb + (((size_t)(b * 8 + grp) * 4096) + p0) * 16 + sub);
            short8 b1 = *(const short8*)(inb + (((size_t)(b * 8 + grp) * 4096) + p1) * 16 + sub);
#pragma unroll
            for (int mt = 0; mt < 4; ++mt) {
                short8 ah = *(const short8*)(s_qh + (size_t)(mt * 16 + li) * 72 + cb);
                short8 al = *(const short8*)(s_ql + (size_t)(mt * 16 + li) * 72 + cb);
                acc[0][mt] = __builtin_amdgcn_mfma_f32_16x16x32_bf16(ah, b0, acc[0][mt], 0, 0, 0);
                acc[0][mt] = __builtin_amdgcn_mfma_f32_16x16x32_bf16(al, b0, acc[0][mt], 0, 0, 0);
                acc[1][mt] = __builtin_amdgcn_mfma_f32_16x16x32_bf16(ah, b1, acc[1][mt], 0, 0, 0);
                acc[1][mt] = __builtin_amdgcn_mfma_f32_16x16x32_bf16(al, b1, acc[1][mt], 0, 0, 0);
            }
        }
        // epilogue: mask + scale, reduce max over the 16 p-lanes, scoreboard per q
#pragma unroll
        for (int mt = 0; mt < 4; ++mt) {
#pragma unroll
            for (int r = 0; r < 4; ++r) {
                float sc = fmaxf(acc[0][mt][r] * rp0 + ng0, acc[1][mt][r] * rp1 + ng1);
                sc = fmaxf(sc, __shfl_xor(sc, 1));
                sc = fmaxf(sc, __shfl_xor(sc, 2));
                sc = fmaxf(sc, __shfl_xor(sc, 4));
                sc = fmaxf(sc, __shfl_xor(sc, 8));
                if (li == 0) atomicMax(&s_best[mt * 16 + quad * 4 + r], mapf(sc));
            }
        }
        __syncthreads();
        if (t < 64 && qs0 + t < nu) atomicMax(scores + b * 4096 + qs0 + t, s_best[t]);
    }
}

// ---------------- K3: MFMA implicit-GEMM conv 3x3 (128->64) + in-LDS sm fixup + bias + GN partials ----------------
// grid (16 rowblk, 4 ocblk, 4 b) = 256 blocks, block 256 = 4 waves (one per output row) — the R7 shape,
// measured best (R8 2-row/512 and R9 direct-global variants both regressed).
__global__ __launch_bounds__(256) void k_conv_mfma(
    const ushort* __restrict__ inb, const ushort* __restrict__ wbh, const ushort* __restrict__ wbl,
    const float* __restrict__ bfuse, const int* __restrict__ unsel, const int* __restrict__ unselN,
    const unsigned* __restrict__ scores, float* __restrict__ smOut,
    float* __restrict__ y, float* __restrict__ gnS1, float* __restrict__ gnS2) {
    const int rowblk = blockIdx.x;
    const int ocblk = blockIdx.y;
    const int b = blockIdx.z;
    const int t = threadIdx.x;
    const int lane = t & 63;
    const int wave = t >> 6;
    const int li = lane & 15;
    const int quad = lane >> 4;
    const int h0 = rowblk * 4;
    const int oc0 = ocblk * 16;
    const int nu = unselN[b];

    __shared__ __align__(16) ushort s_in[6 * 66 * 40];   // [r][c][32ic pad40] halves
    __shared__ __align__(16) ushort s_wh[9 * 16 * 40];   // [tap][oc][32ic pad40]
    __shared__ __align__(16) ushort s_wl[9 * 16 * 40];
    __shared__ float red1[256];
    __shared__ float red2[256];

    // designated block per batch finalizes the sm output for unselected q
    if (rowblk == 0 && ocblk == 0) {
        for (int qi = t; qi < nu; qi += 256) {
            float sm = unmapf(scores[b * 4096 + qi]) * 0.5f + 0.5f;
            smOut[b * 4096 + unsel[b * 4096 + qi]] = sm;
        }
    }

    f32x4 acc[4];
#pragma unroll
    for (int j = 0; j < 4; ++j) acc[j] = (f32x4){0.f, 0.f, 0.f, 0.f};

    for (int chunk = 0; chunk < 4; ++chunk) {
        __syncthreads();
        // stage input slab: rows h0-1..h0+4, cols -1..64, 32 ic (4 x 16B parts per cell)
        // inb layout: [b][8 grp][sp][16 halves]; chunk c covers grps {2c, 2c+1}
        for (int idx = t; idx < 1584; idx += 256) {
            int part = idx & 3;
            int cell = idx >> 2;
            int r = cell / 66;
            int c = cell - r * 66;
            int h = h0 + r - 1;
            int w = c - 1;
            uint4 v = make_uint4(0u, 0u, 0u, 0u);
            if ((unsigned)h < 64u && (unsigned)w < 64u) {
                int grp = 2 * chunk + (part >> 1);
                int sub = part & 1;
                v = *(const uint4*)(inb + (((size_t)(b * 8 + grp) * 4096 + h * 64 + w) * 16 + sub * 8));
            }
            *(uint4*)(s_in + (size_t)cell * 40 + part * 8) = v;
        }
        // stage weights: {hi,lo} x 9 taps x 16 oc x 4 parts
        const int ic0 = chunk * 32;
        for (int idx = t; idx < 1152; idx += 256) {
            int part = idx & 3;
            int uu = idx >> 2;              // hl*144 + tap*16 + o
            int hl = uu / 144;
            int rem = uu - hl * 144;
            int tap = rem >> 4;
            int o = rem & 15;
            const ushort* src = (hl ? wbl : wbh) + ((size_t)(tap * 64 + oc0 + o) * 128 + ic0 + part * 8);
            uint4 v = *(const uint4*)src;
            ushort* dst = (hl ? s_wl : s_wh) + ((size_t)(tap * 16 + o) * 40 + part * 8);
            *(uint4*)dst = v;
        }
        // in-LDS sm rescale of unselected positions (scaled half = chunks 0,1 only)
        if (chunk < 2) {
            __syncthreads();   // staging visible before modification
            for (int idx = t; idx < nu * 4; idx += 256) {
                int qi = idx >> 2;
                int part = idx & 3;
                int q = unsel[b * 4096 + qi];
                int hq = q >> 6, wq = q & 63;
                int r = hq - h0 + 1;
                if ((unsigned)r < 6u) {
                    float sm = unmapf(scores[b * 4096 + qi]) * 0.5f + 0.5f;
                    ushort* ptr = s_in + (size_t)(r * 66 + wq + 1) * 40 + part * 8;
                    ushort hv[8];
                    *(uint4*)hv = *(const uint4*)ptr;
#pragma unroll
                    for (int j = 0; j < 8; ++j) hv[j] = f2bf(bf2f(hv[j]) * sm);
                    *(uint4*)ptr = *(const uint4*)hv;
                }
            }
        }
        __syncthreads();
#pragma unroll
        for (int kh = 0; kh < 3; ++kh) {
            const int r = wave + kh;
#pragma unroll
            for (int kw = 0; kw < 3; ++kw) {
                const int tap = kh * 3 + kw;
                short8 ah = *(const short8*)(s_wh + (size_t)(tap * 16 + li) * 40 + quad * 8);
                short8 al = *(const short8*)(s_wl + (size_t)(tap * 16 + li) * 40 + quad * 8);
#pragma unroll
                for (int j = 0; j < 4; ++j) {
                    int c = j * 16 + li + kw;
                    short8 bv = *(const short8*)(s_in + ((size_t)(r * 66 + c) * 40 + quad * 8));
                    acc[j] = __builtin_amdgcn_mfma_f32_16x16x32_bf16(ah, bv, acc[j], 0, 0, 0);
                    acc[j] = __builtin_amdgcn_mfma_f32_16x16x32_bf16(al, bv, acc[j], 0, 0, 0);
                }
            }
        }
    }
    // epilogue: bias, store (coalesced: col=lane&15 is w), GN partial sums
    float bias[4];
#pragma unroll
    for (int reg = 0; reg < 4; ++reg) bias[reg] = bfuse[oc0 + quad * 4 + reg];
    float s1 = 0.f, s2 = 0.f;
    const int hrow = h0 + wave;
#pragma unroll
    for (int j = 0; j < 4; ++j) {
#pragma unroll
        for (int reg = 0; reg < 4; ++reg) {
            float v = acc[j][reg] + bias[reg];
            y[((size_t)(b * 64 + oc0 + quad * 4 + reg)) * HW + hrow * 64 + j * 16 + li] = v;
            s1 += v; s2 += v * v;
        }
    }
    red1[t] = s1; red2[t] = s2;
    __syncthreads();
    for (int s = 128; s > 0; s >>= 1) {
        if (t < s) { red1[t] += red1[t + s]; red2[t] += red2[t + s]; }
        __syncthreads();
    }
    if (t == 0) {
        atomicAdd(&gnS1[b], red1[0]);
        atomicAdd(&gnS2[b], red2[0]);
    }
}

// ---------------- K4: GroupNorm(1 group) + affine + ReLU, in-place on out ----------------
__global__ void k_gn(float* __restrict__ out, const float* __restrict__ gnS1, const float* __restrict__ gnS2,
                     const float* __restrict__ gamma, const float* __restrict__ beta) {
    const int e = (blockIdx.x * 256 + threadIdx.x) * 4;
    const int b = e >> 18;
    const int c = (e >> 12) & 63;
    const float inv = 1.0f / 262144.0f;
    float mu = gnS1[b] * inv;
    float var = gnS2[b] * inv - mu * mu;
    float rs = rsqrtf(var + 1e-5f);
    float scale = rs * gamma[c];
    float shift = beta[c] - mu * scale;
    float4 v = *(const float4*)(out + e);
    float4 o;
    o.x = fmaxf(v.x * scale + shift, 0.0f);
    o.y = fmaxf(v.y * scale + shift, 0.0f);
    o.z = fmaxf(v.z * scale + shift, 0.0f);
    o.w = fmaxf(v.w * scale + shift, 0.0f);
    *(float4*)(out + e) = o;
}

extern "C" void kernel_launch(void* const* d_in, const int* in_sizes, int n_in,
                              void* d_out, int out_size, void* d_ws, size_t ws_size,
                              hipStream_t stream) {
    const float* fdm   = (const float*)d_in[0];
    const float* x     = (const float*)d_in[1];
    const float* Wf    = (const float*)d_in[2];
    const float* bfuse = (const float*)d_in[3];
    const float* gamma = (const float*)d_in[4];
    const float* beta  = (const float*)d_in[5];
    float* out = (float*)d_out;
    float* ws  = (float*)d_ws;

    // workspace layout (float offsets, all 16B-aligned)
    float*    rn      = ws;                         // 16384
    float*    pooledM = rn + 16384;                 // 16384
    int*      unsel   = (int*)(pooledM + 16384);    // 16384
    unsigned* scores  = (unsigned*)(unsel + 16384); // 16384
    float*    thre    = (float*)(scores + 16384);   // 4
    int*      unselN  = (int*)(thre + 4);           // 4
    float*    gnS1    = (float*)(unselN + 4);       // 4
    float*    gnS2    = gnS1 + 4;                   // 4
    ushort*   wbh     = (ushort*)(gnS2 + 4);        // 73728 halves
    ushort*   wbl     = wbh + 73728;                // 73728 halves
    ushort*   inb     = wbl + 73728;                // 4194304 halves (8 MB)

    float* yout  = out;                             // conv output in out[0..1M), GN in-place
    float* smOut = out + 1048576;                   // second output

    k_pnp<<<dim3(296), dim3(256), 0, stream>>>(fdm, x, Wf, pooledM, thre, unsel, unselN,
                                               scores, gnS1, gnS2, rn, smOut, inb, wbh, wbl);
    k_score<<<dim3(32, 4), dim3(256), 0, stream>>>(rn, pooledM, thre, unsel, unselN, inb, scores);
    k_conv_mfma<<<dim3(16, 4, 4), dim3(256), 0, stream>>>(inb, wbh, wbl, bfuse, unsel, unselN,
                                                          scores, smOut, yout, gnS1, gnS2);
    k_gn<<<dim3(1024), dim3(256), 0, stream>>>(yout, gnS1, gnS2, gamma, beta);
}

// Round 12
// 99.938 us; speedup vs baseline: 1.2751x; 1.0692x over previous
//
#include <hip/hip_runtime.h>
#include <math.h>

// Problem constants: b=4, f=64, h=w=64, HW=4096
// Inputs: fdm [4,1,128,128], x [4,64,64,64], W_fuse [64,128,3,3], b_fuse [64], gamma [64], beta [64]
// Outputs concatenated: x0 [4,64,64,64] (1048576 f32) then sm [4,1,64,64] (16384 f32)

#define HW 4096
#define NCH 64

typedef __attribute__((ext_vector_type(8))) short short8;
typedef __attribute__((ext_vector_type(4))) float f32x4;

static __device__ __forceinline__ ushort f2bf(float f) {
    unsigned u = __float_as_uint(f);
    unsigned r = (u + 0x7fffu + ((u >> 16) & 1u)) >> 16;   // RNE
    return (ushort)r;
}
static __device__ __forceinline__ float bf2f(ushort h) {
    return __uint_as_float(((unsigned)h) << 16);
}
// order-preserving float <-> uint map for atomicMax
static __device__ __forceinline__ unsigned mapf(float f) {
    unsigned u = __float_as_uint(f);
    return u ^ ((unsigned)((int)u >> 31) | 0x80000000u);
}
static __device__ __forceinline__ float unmapf(unsigned u) {
    unsigned b = (u & 0x80000000u) ? (u ^ 0x80000000u) : ~u;
    return __uint_as_float(b);
}
// async global->LDS, 16B per lane; LDS dest = wave-uniform base + lane*16
static __device__ __forceinline__ void gl2lds(const void* g, void* l) {
    __builtin_amdgcn_global_load_lds((const __attribute__((address_space(1))) void*)g,
                                     (__attribute__((address_space(3))) void*)l, 16, 0, 0);
}

// ---------------- K1: pool (blk 0-3) || norm+bf16-prep (blk 4-259) || weight-prep (blk 260-295) ----------------
// inb layout: [b][8 grp][sp 4096][16 halves]; grp 0-3 = sm*x ch {0..63}, grp 4-7 = x ch {0..63}.
// Both halves written with scale=1; conv rescales the ~50 unselected cells in LDS.
__global__ __launch_bounds__(256) void k_pnp(
    const float* __restrict__ fdm, const float* __restrict__ x, const float* __restrict__ W,
    float* __restrict__ pooledOut, float* __restrict__ threOut,
    int* __restrict__ unsel, int* __restrict__ unselN, unsigned* __restrict__ scores,
    float* __restrict__ gnS1, float* __restrict__ gnS2,
    float* __restrict__ rn, float* __restrict__ smOut, ushort* __restrict__ inb,
    ushort* __restrict__ wbh, ushort* __restrict__ wbl, uint4* __restrict__ zpage) {
    const int t = threadIdx.x;
    if (blockIdx.x < 4) {
        // ---- pool path ----
        const int b = blockIdx.x;
        __shared__ float pooled[4096];
        __shared__ float red[256];
        __shared__ int cnt;
        const float* fb = fdm + b * 16384;
        float lmax = -1.0f;
#pragma unroll
        for (int it = 0; it < 8; ++it) {
            int id2 = it * 256 + t;
            int i = id2 >> 5;
            int j2 = id2 & 31;
            const float* base = fb + i * 256 + j2 * 4;
            float4 a = *(const float4*)base;
            float4 c = *(const float4*)(base + 128);
            float p0 = fmaxf(fmaxf(a.x, a.y), fmaxf(c.x, c.y));
            float p1 = fmaxf(fmaxf(a.z, a.w), fmaxf(c.z, c.w));
            pooled[i * 64 + j2 * 2]     = p0;
            pooled[i * 64 + j2 * 2 + 1] = p1;
            lmax = fmaxf(lmax, fmaxf(p0, p1));
        }
        red[t] = lmax;
        __syncthreads();
        for (int s = 128; s > 0; s >>= 1) {
            if (t < s) red[t] = fmaxf(red[t], red[t + s]);
            __syncthreads();
        }
        __shared__ float thre_s;
        if (t == 0) {
            thre_s = fminf(0.5f, red[0] / 3.0f);   // exact reference fp32 rounding
            cnt = 0;
            gnS1[b] = 0.0f; gnS2[b] = 0.0f;
            if (b == 0) *zpage = make_uint4(0u, 0u, 0u, 0u);   // zero-page for conv OOB lanes
        }
        __syncthreads();
        const float th = thre_s;
#pragma unroll
        for (int it = 0; it < 4; ++it) {
            int idx = (it * 256 + t) * 4;
            *(float4*)(pooledOut + b * 4096 + idx) = *(const float4*)(pooled + idx);
        }
        for (int idx = t; idx < 4096; idx += 256) {
            scores[b * 4096 + idx] = 0u;           // zero-init scoreboard (ws is poisoned)
            if (!(pooled[idx] >= th)) {
                int pos = atomicAdd(&cnt, 1);
                unsel[b * 4096 + pos] = idx;
            }
        }
        __syncthreads();
        if (t == 0) { unselN[b] = cnt; threOut[b] = th; }
    } else if (blockIdx.x < 260) {
        // ---- norm + prep path ----
        __shared__ float s_part[4][64];
        const int n = blockIdx.x - 4;       // 0..255
        const int b = n >> 6;
        const int pbase = (n & 63) * 64;
        const int wv = t >> 6;              // channel group of 16
        const int l = t & 63;               // position within 64-slice
        const int sp = pbase + l;
        const float* xp = x + b * (NCH * HW) + sp;
        float xv[16];
        float ss = 0.f;
#pragma unroll
        for (int i = 0; i < 16; ++i) {
            float a = xp[(wv * 16 + i) * HW];
            xv[i] = a;
            ss += a * a;
        }
        s_part[wv][l] = ss;
        ushort h[16];
#pragma unroll
        for (int i = 0; i < 16; ++i) h[i] = f2bf(xv[i]);
        size_t dst1 = ((size_t)(b * 8 + wv) * 4096 + sp) * 16;
        size_t dst2 = ((size_t)(b * 8 + 4 + wv) * 4096 + sp) * 16;
        *(uint4*)(inb + dst1)     = *(const uint4*)h;
        *(uint4*)(inb + dst1 + 8) = *(const uint4*)(h + 8);
        *(uint4*)(inb + dst2)     = *(const uint4*)h;
        *(uint4*)(inb + dst2 + 8) = *(const uint4*)(h + 8);
        __syncthreads();
        if (t < 64) {
            float s = s_part[0][l] + s_part[1][l] + s_part[2][l] + s_part[3][l];
            int g = b * HW + pbase + l;
            rn[g] = 1.0f / fmaxf(sqrtf(s), 1e-8f);
            smOut[g] = 1.0f;
        }
    } else {
        // ---- weight prep: bf16 hi/lo, layout [tap][oc][ic128] ----
        const int u = (blockIdx.x - 260) * 256 + t;   // 0..9215 = tap*1024 + oc*16 + g
        const int tap = u >> 10;
        const int rem = u & 1023;
        const int oc = rem >> 4;
        const int g = rem & 15;
        ushort hh[8], ll[8];
#pragma unroll
        for (int j = 0; j < 8; ++j) {
            int ic = g * 8 + j;
            float v = W[(oc * 128 + ic) * 9 + tap];
            ushort hb = f2bf(v);
            hh[j] = hb;
            ll[j] = f2bf(v - bf2f(hb));
        }
        *(uint4*)(wbh + (size_t)u * 8) = *(const uint4*)hh;
        *(uint4*)(wbl + (size_t)u * 8) = *(const uint4*)ll;
    }
}

// ---------------- K2: score via MFMA — D[q,p] = q_hat . x_p, masked max over p ----------------
// grid (32 p-strips, 4 b), 256 threads = 4 waves. Strip = 128 p, wave covers 32 p (2 n-tiles).
// A = q_hat hi/lo gathered into LDS from bf16 inb (rq prefolded, coalesced 16B loads — R11-validated);
// B = x bf16 read DIRECTLY from inb grp 4-7 (global).
__global__ __launch_bounds__(256) void k_score(
    const float* __restrict__ rn, const float* __restrict__ pooledM, const float* __restrict__ threArr,
    const int* __restrict__ unsel, const int* __restrict__ unselN,
    const ushort* __restrict__ inb, unsigned* __restrict__ scores) {
    const int b = blockIdx.y;
    const int n0 = blockIdx.x * 128;
    const int t = threadIdx.x;
    const int lane = t & 63;
    const int wave = t >> 6;
    const int li = lane & 15;
    const int quad = lane >> 4;
    const int nu = unselN[b];
    if (nu == 0) return;

    __shared__ __align__(16) ushort s_qh[64 * 72];    // [q_local][64 c] pad 72
    __shared__ __align__(16) ushort s_ql[64 * 72];
    __shared__ unsigned s_best[64];

    const float th = threArr[b];
    const int p0 = n0 + (2 * wave) * 16 + li;
    const int p1 = n0 + (2 * wave + 1) * 16 + li;
    const float rp0 = rn[b * 4096 + p0];
    const float rp1 = rn[b * 4096 + p1];
    const float ng0 = (pooledM[b * 4096 + p0] >= th) ? 0.0f : -INFINITY;
    const float ng1 = (pooledM[b * 4096 + p1] >= th) ? 0.0f : -INFINITY;

    for (int qs0 = 0; qs0 < nu; qs0 += 64) {
        __syncthreads();   // iter>0: prior s_best reads done
        // gather 64 q rows (hi/lo) from plain-x bf16 inb (grp 4-7), rq prefolded; zero beyond nu
        for (int idx = t; idx < 512; idx += 256) {
            int q_l = idx >> 3;          // 0..63
            int part = idx & 7;          // grp = 4 + (part>>1), sub = (part&1)*8
            int qg = qs0 + q_l;
            int q = 0;
            float rq = 0.0f;
            if (qg < nu) {
                q = unsel[b * 4096 + qg];
                rq = rn[b * 4096 + q];
            }
            uint4 raw = *(const uint4*)(inb + (((size_t)(b * 8 + 4 + (part >> 1)) * 4096) + q) * 16 + (part & 1) * 8);
            ushort hv[8]; *(uint4*)hv = raw;
            ushort hh[8], ll[8];
#pragma unroll
            for (int j = 0; j < 8; ++j) {
                float v = bf2f(hv[j]) * rq;
                hh[j] = f2bf(v);
                ll[j] = f2bf(v - bf2f(hh[j]));
            }
            int c0 = (part >> 1) * 16 + (part & 1) * 8;
            *(uint4*)(s_qh + q_l * 72 + c0) = *(const uint4*)hh;
            *(uint4*)(s_ql + q_l * 72 + c0) = *(const uint4*)ll;
        }
        if (t < 64) s_best[t] = 0u;
        __syncthreads();

        f32x4 acc[2][4];
#pragma unroll
        for (int nt = 0; nt < 2; ++nt)
#pragma unroll
            for (int mt = 0; mt < 4; ++mt) acc[nt][mt] = (f32x4){0.f, 0.f, 0.f, 0.f};
#pragma unroll
        for (int k0 = 0; k0 < 2; ++k0) {
            const int cb = k0 * 32 + quad * 8;
            const int grp = 4 + (cb >> 4);
            const int sub = cb & 15;
            short8 b0 = *(const short8*)(inb + (((size_t)(b * 8 + grp) * 4096) + p0) * 16 + sub);
            short8 b1 = *(const short8*)(inb + (((size_t)(b * 8 + grp) * 4096) + p1) * 16 + sub);
#pragma unroll
            for (int mt = 0; mt < 4; ++mt) {
                short8 ah = *(const short8*)(s_qh + (size_t)(mt * 16 + li) * 72 + cb);
                short8 al = *(const short8*)(s_ql + (size_t)(mt * 16 + li) * 72 + cb);
                acc[0][mt] = __builtin_amdgcn_mfma_f32_16x16x32_bf16(ah, b0, acc[0][mt], 0, 0, 0);
                acc[0][mt] = __builtin_amdgcn_mfma_f32_16x16x32_bf16(al, b0, acc[0][mt], 0, 0, 0);
                acc[1][mt] = __builtin_amdgcn_mfma_f32_16x16x32_bf16(ah, b1, acc[1][mt], 0, 0, 0);
                acc[1][mt] = __builtin_amdgcn_mfma_f32_16x16x32_bf16(al, b1, acc[1][mt], 0, 0, 0);
            }
        }
        // epilogue: mask + scale, reduce max over the 16 p-lanes, scoreboard per q
#pragma unroll
        for (int mt = 0; mt < 4; ++mt) {
#pragma unroll
            for (int r = 0; r < 4; ++r) {
                float sc = fmaxf(acc[0][mt][r] * rp0 + ng0, acc[1][mt][r] * rp1 + ng1);
                sc = fmaxf(sc, __shfl_xor(sc, 1));
                sc = fmaxf(sc, __shfl_xor(sc, 2));
                sc = fmaxf(sc, __shfl_xor(sc, 4));
                sc = fmaxf(sc, __shfl_xor(sc, 8));
                if (li == 0) atomicMax(&s_best[mt * 16 + quad * 4 + r], mapf(sc));
            }
        }
        __syncthreads();
        if (t < 64 && qs0 + t < nu) atomicMax(scores + b * 4096 + qs0 + t, s_best[t]);
    }
}

// ---------------- K3: MFMA conv 3x3 (128->64), async global_load_lds staging + LDS double-buffer ----------------
// grid (16 rowblk, 4 ocblk, 4 b) = 256 blocks, block 256 = 4 waves (one per output row).
// LDS layout [part][cell]x16B (global_load_lds lands lane l at base+16l; wave w stages part w).
// Chunk order 2,3,0,1 (fixup chunks last): next chunk's loads fly during current chunk's MFMA.
__global__ __launch_bounds__(256) void k_conv_mfma(
    const ushort* __restrict__ inb, const ushort* __restrict__ wbh, const ushort* __restrict__ wbl,
    const float* __restrict__ bfuse, const int* __restrict__ unsel, const int* __restrict__ unselN,
    const unsigned* __restrict__ scores, float* __restrict__ smOut, const uint4* __restrict__ zpage,
    float* __restrict__ y, float* __restrict__ gnS1, float* __restrict__ gnS2) {
    const int rowblk = blockIdx.x;
    const int ocblk = blockIdx.y;
    const int b = blockIdx.z;
    const int t = threadIdx.x;
    const int lane = t & 63;
    const int wave = t >> 6;      // staging part id AND output row within block
    const int li = lane & 15;
    const int quad = lane >> 4;
    const int h0 = rowblk * 4;
    const int oc0 = ocblk * 16;
    const int nu = unselN[b];

    __shared__ __align__(16) ushort s_in[2][4 * 396 * 8];   // [buf][part][cell 396]x16B = 2 x 25344 B
    __shared__ __align__(16) ushort s_w[2][4 * 288 * 8];    // [buf][part][hi 144 | lo 144]x16B = 2 x 18432 B
    __shared__ float red1[256];
    __shared__ float red2[256];

    // designated block per batch finalizes the sm output for unselected q
    if (rowblk == 0 && ocblk == 0) {
        for (int qi = t; qi < nu; qi += 256) {
            float sm = unmapf(scores[b * 4096 + qi]) * 0.5f + 0.5f;
            smOut[b * 4096 + unsel[b * 4096 + qi]] = sm;
        }
    }

    f32x4 acc[4];
#pragma unroll
    for (int j = 0; j < 4; ++j) acc[j] = (f32x4){0.f, 0.f, 0.f, 0.f};

    // async-stage chunk -> buf: this wave stages part = wave
    auto issue = [&](int chunk, int buf) {
        const int part = wave;
        const int grp = 2 * chunk + (part >> 1);
        const int sub = (part & 1) * 8;
        const ushort* gbase = inb + (((size_t)(b * 8 + grp)) * 4096) * 16 + sub;
        ushort* lin = &s_in[buf][part * 3168];
#pragma unroll
        for (int i = 0; i < 7; ++i) {
            int cell = i * 64 + lane;
            if (cell < 396) {
                int r = cell / 66;
                int c = cell - r * 66;
                int h = h0 + r - 1;
                int w = c - 1;
                bool ok = ((unsigned)h < 64u) && ((unsigned)w < 64u);
                const void* src = ok ? (const void*)(gbase + (size_t)(h * 64 + w) * 16) : (const void*)zpage;
                gl2lds(src, lin + i * 512);
            }
        }
        const int ic0 = chunk * 32;
        ushort* lw = &s_w[buf][part * 2304];
#pragma unroll
        for (int i = 0; i < 5; ++i) {
            int j = i * 64 + lane;
            if (j < 288) {
                int hl = (j >= 144);
                int e = j - hl * 144;
                int tap = e >> 4;
                int o = e & 15;
                const ushort* src = (hl ? wbl : wbh) + ((size_t)(tap * 64 + oc0 + o) * 128 + ic0 + part * 8);
                gl2lds(src, lw + i * 512);
            }
        }
    };

    issue(2, 0);   // prologue: first chunk (order 2,3,0,1)

    for (int a = 0; a < 4; ++a) {
        const int chunk = a ^ 2;           // 2,3,0,1
        const int buf = a & 1;
        __syncthreads();                   // drains this buf's async loads; guards LDS reuse
        if (chunk < 2) {
            // in-LDS sm rescale of unselected positions (scaled-copy chunks 0,1)
            for (int idx = t; idx < nu * 4; idx += 256) {
                int qi = idx >> 2;
                int part = idx & 3;
                int q = unsel[b * 4096 + qi];
                int hq = q >> 6, wq = q & 63;
                int r = hq - h0 + 1;
                if ((unsigned)r < 6u) {
                    float sm = unmapf(scores[b * 4096 + qi]) * 0.5f + 0.5f;
                    ushort* ptr = &s_in[buf][part * 3168 + (r * 66 + wq + 1) * 8];
                    ushort hv[8];
                    *(uint4*)hv = *(const uint4*)ptr;
#pragma unroll
                    for (int j = 0; j < 8; ++j) hv[j] = f2bf(bf2f(hv[j]) * sm);
                    *(uint4*)ptr = *(const uint4*)hv;
                }
            }
            __syncthreads();
        }
        if (a < 3) issue((a + 1) ^ 2, 1 - buf);   // next chunk's loads fly during this chunk's MFMA
        {
            const ushort* sin = &s_in[buf][quad * 3168];
            const ushort* swq = &s_w[buf][quad * 2304];
#pragma unroll
            for (int kh = 0; kh < 3; ++kh) {
                const int r = wave + kh;
#pragma unroll
                for (int kw = 0; kw < 3; ++kw) {
                    const int tap = kh * 3 + kw;
                    short8 ah = *(const short8*)(swq + (tap * 16 + li) * 8);
                    short8 al = *(const short8*)(swq + 1152 + (tap * 16 + li) * 8);
#pragma unroll
                    for (int j = 0; j < 4; ++j) {
                        int c = j * 16 + li + kw;
                        short8 bv = *(const short8*)(sin + (r * 66 + c) * 8);
                        acc[j] = __builtin_amdgcn_mfma_f32_16x16x32_bf16(ah, bv, acc[j], 0, 0, 0);
                        acc[j] = __builtin_amdgcn_mfma_f32_16x16x32_bf16(al, bv, acc[j], 0, 0, 0);
                    }
                }
            }
        }
    }
    // epilogue: bias, store (coalesced: col=lane&15 is w), GN partial sums
    float bias[4];
#pragma unroll
    for (int reg = 0; reg < 4; ++reg) bias[reg] = bfuse[oc0 + quad * 4 + reg];
    float s1 = 0.f, s2 = 0.f;
    const int hrow = h0 + wave;
#pragma unroll
    for (int j = 0; j < 4; ++j) {
#pragma unroll
        for (int reg = 0; reg < 4; ++reg) {
            float v = acc[j][reg] + bias[reg];
            y[((size_t)(b * 64 + oc0 + quad * 4 + reg)) * HW + hrow * 64 + j * 16 + li] = v;
            s1 += v; s2 += v * v;
        }
    }
    red1[t] = s1; red2[t] = s2;
    __syncthreads();
    for (int s = 128; s > 0; s >>= 1) {
        if (t < s) { red1[t] += red1[t + s]; red2[t] += red2[t + s]; }
        __syncthreads();
    }
    if (t == 0) {
        atomicAdd(&gnS1[b], red1[0]);
        atomicAdd(&gnS2[b], red2[0]);
    }
}

// ---------------- K4: GroupNorm(1 group) + affine + ReLU, in-place on out ----------------
__global__ void k_gn(float* __restrict__ out, const float* __restrict__ gnS1, const float* __restrict__ gnS2,
                     const float* __restrict__ gamma, const float* __restrict__ beta) {
    const int e = (blockIdx.x * 256 + threadIdx.x) * 4;
    const int b = e >> 18;
    const int c = (e >> 12) & 63;
    const float inv = 1.0f / 262144.0f;
    float mu = gnS1[b] * inv;
    float var = gnS2[b] * inv - mu * mu;
    float rs = rsqrtf(var + 1e-5f);
    float scale = rs * gamma[c];
    float shift = beta[c] - mu * scale;
    float4 v = *(const float4*)(out + e);
    float4 o;
    o.x = fmaxf(v.x * scale + shift, 0.0f);
    o.y = fmaxf(v.y * scale + shift, 0.0f);
    o.z = fmaxf(v.z * scale + shift, 0.0f);
    o.w = fmaxf(v.w * scale + shift, 0.0f);
    *(float4*)(out + e) = o;
}

extern "C" void kernel_launch(void* const* d_in, const int* in_sizes, int n_in,
                              void* d_out, int out_size, void* d_ws, size_t ws_size,
                              hipStream_t stream) {
    const float* fdm   = (const float*)d_in[0];
    const float* x     = (const float*)d_in[1];
    const float* Wf    = (const float*)d_in[2];
    const float* bfuse = (const float*)d_in[3];
    const float* gamma = (const float*)d_in[4];
    const float* beta  = (const float*)d_in[5];
    float* out = (float*)d_out;
    float* ws  = (float*)d_ws;

    // workspace layout (float offsets, all 16B-aligned)
    float*    rn      = ws;                         // 16384
    float*    pooledM = rn + 16384;                 // 16384
    int*      unsel   = (int*)(pooledM + 16384);    // 16384
    unsigned* scores  = (unsigned*)(unsel + 16384); // 16384
    float*    thre    = (float*)(scores + 16384);   // 4
    int*      unselN  = (int*)(thre + 4);           // 4
    float*    gnS1    = (float*)(unselN + 4);       // 4
    float*    gnS2    = gnS1 + 4;                   // 4
    uint4*    zpage   = (uint4*)(gnS2 + 4);         // 16 B zero-page (conv OOB lanes)
    ushort*   wbh     = (ushort*)(zpage + 1);       // 73728 halves
    ushort*   wbl     = wbh + 73728;                // 73728 halves
    ushort*   inb     = wbl + 73728;                // 4194304 halves (8 MB)

    float* yout  = out;                             // conv output in out[0..1M), GN in-place
    float* smOut = out + 1048576;                   // second output

    k_pnp<<<dim3(296), dim3(256), 0, stream>>>(fdm, x, Wf, pooledM, thre, unsel, unselN,
                                               scores, gnS1, gnS2, rn, smOut, inb, wbh, wbl, zpage);
    k_score<<<dim3(32, 4), dim3(256), 0, stream>>>(rn, pooledM, thre, unsel, unselN, inb, scores);
    k_conv_mfma<<<dim3(16, 4, 4), dim3(256), 0, stream>>>(inb, wbh, wbl, bfuse, unsel, unselN,
                                                          scores, smOut, zpage, yout, gnS1, gnS2);
    k_gn<<<dim3(1024), dim3(256), 0, stream>>>(yout, gnS1, gnS2, gamma, beta);
}